// Round 3
// baseline (2818.629 us; speedup 1.0000x reference)
//
#include <hip/hip_runtime.h>
#include <hip/hip_bf16.h>

// ---------------------------------------------------------------------------
// Conv-TasNet TCN, bf16-MFMA v2.
// All GEMMs are CLEAN bf16 GEMMs (A and B raw bf16) staged via
// global_load_lds_dwordx4 with both-sides XOR bank-swizzle.
//   - GN2 folded into res/skip weights: res = rs*(W.g2)@U + (v - mean*rs*u) + b
//   - OUT keeps an fp32 master + bf16 shadow (next pw's B operand)
// Layout: activations [B][TP=4096][C] time-major. fp32: OUT/SKIP, stats.
// ---------------------------------------------------------------------------

#define T_  4000
#define TP_ 4096
#define B_  4

typedef __attribute__((ext_vector_type(8))) short  s8v;
typedef __attribute__((ext_vector_type(4))) float  f32x4;
typedef __attribute__((ext_vector_type(4))) unsigned short u16x4;

__device__ __forceinline__ float bf2f(unsigned short u) {
  unsigned int i = ((unsigned int)u) << 16;
  float f; __builtin_memcpy(&f, &i, 4); return f;
}
__device__ __forceinline__ unsigned short f2bf(float f) {
  unsigned int i; __builtin_memcpy(&i, &f, 4);
  unsigned int r = i + 0x7fffu + ((i >> 16) & 1u);
  return (unsigned short)(r >> 16);
}

__device__ __forceinline__ void g2lds16(const void* g, void* l) {
  __builtin_amdgcn_global_load_lds(
      (const __attribute__((address_space(1))) unsigned int*)g,
      (__attribute__((address_space(3))) unsigned int*)l, 16, 0, 0);
}

// ---------------- per-sample sum/sumsq over contiguous [C*T] ---------------
__global__ __launch_bounds__(256) void gn_stats(const float* __restrict__ X,
                                                float* __restrict__ statsOut, int n) {
  const int b = blockIdx.y;
  const float4* xp = (const float4*)(X + (size_t)b * n);
  const int n4 = n >> 2;
  float s1 = 0.f, s2 = 0.f;
  for (int idx = blockIdx.x * 256 + threadIdx.x; idx < n4; idx += gridDim.x * 256) {
    float4 v = xp[idx];
    s1 += v.x + v.y + v.z + v.w;
    s2 += v.x * v.x + v.y * v.y + v.z * v.z + v.w * v.w;
  }
  __shared__ float red[512];
  red[threadIdx.x] = s1; red[256 + threadIdx.x] = s2;
  __syncthreads();
  for (int off = 128; off > 0; off >>= 1) {
    if (threadIdx.x < off) {
      red[threadIdx.x] += red[threadIdx.x + off];
      red[256 + threadIdx.x] += red[256 + threadIdx.x + off];
    }
    __syncthreads();
  }
  if (threadIdx.x == 0) {
    atomicAdd(&statsOut[b * 2 + 0], red[0]);
    atomicAdd(&statsOut[b * 2 + 1], red[256]);
  }
}

// ---------------- weight prep ----------------------------------------------
__global__ __launch_bounds__(256) void cvt_bf(const float* __restrict__ s,
                                              unsigned short* __restrict__ d, int n) {
  for (int i = blockIdx.x * 256 + threadIdx.x; i < n; i += gridDim.x * 256)
    d[i] = f2bf(s[i]);
}

// GN2 fold: Wg[i][m][h] = bf16(w[m,h]*g2[i,h]); u=sum(w*g2); v=sum(w*b2)
__global__ __launch_bounds__(256) void fold_rs(
    const float* __restrict__ rw, const float* __restrict__ sw,
    const float* __restrict__ g2a, const float* __restrict__ b2a,
    unsigned short* __restrict__ Wg, float* __restrict__ Ucb,
    float* __restrict__ Vcb) {
  const int row = blockIdx.x;                 // i*256 + m
  const int i = row >> 8, m = row & 255;
  const float* src = (m < 128) ? rw + ((size_t)i * 128 + m) * 512
                               : sw + ((size_t)i * 128 + (m - 128)) * 512;
  const float* g = g2a + (size_t)i * 512;
  const float* bb = b2a + (size_t)i * 512;
  unsigned short* dst = Wg + (size_t)row * 512;
  float u = 0.f, v = 0.f;
  for (int h = threadIdx.x; h < 512; h += 256) {
    float wgt = src[h] * g[h];
    dst[h] = f2bf(wgt);
    u += wgt; v += src[h] * bb[h];
  }
  __shared__ float red[512];
  red[threadIdx.x] = u; red[256 + threadIdx.x] = v;
  __syncthreads();
  for (int off = 128; off > 0; off >>= 1) {
    if (threadIdx.x < off) {
      red[threadIdx.x] += red[threadIdx.x + off];
      red[256 + threadIdx.x] += red[256 + threadIdx.x + off];
    }
    __syncthreads();
  }
  if (threadIdx.x == 0) { Ucb[row] = red[0]; Vcb[row] = red[256]; }
}

// prelu + bf16 convert (heads input prep)
__global__ __launch_bounds__(256) void prelu_cvt(const float* __restrict__ S,
                                                 unsigned short* __restrict__ D,
                                                 const float* __restrict__ ap, int n) {
  const float a = ap[0];
  for (int i = blockIdx.x * 256 + threadIdx.x; i < n; i += gridDim.x * 256) {
    float v = S[i];
    v = v >= 0.f ? v : a * v;
    D[i] = f2bf(v);
  }
}

// ---------------- input transpose + GN affine + bf16 -----------------------
__global__ __launch_bounds__(256) void tin(const float* __restrict__ X,
                                           unsigned short* __restrict__ Xt,
                                           const float* __restrict__ g,
                                           const float* __restrict__ bt,
                                           const float* __restrict__ sIn, float invN) {
  const int b = blockIdx.z, c0 = blockIdx.y * 64, t0 = blockIdx.x * 64;
  __shared__ float tile[64][65];
  const int tid = threadIdx.x;
  const float mean = sIn[b * 2] * invN;
  const float rs = rsqrtf(sIn[b * 2 + 1] * invN - mean * mean + 1e-8f);
  {
    const int cl = tid >> 2, tq = (tid & 3) * 16;
    const float* Xr = X + ((size_t)b * 256 + c0 + cl) * T_;
#pragma unroll
    for (int j = 0; j < 4; ++j) {
      int tt = t0 + tq + j * 4;
      float4 v;
      if (tt + 3 < T_) v = *(const float4*)(Xr + tt);
      else {
        v.x = (tt + 0 < T_) ? Xr[tt + 0] : 0.f;
        v.y = (tt + 1 < T_) ? Xr[tt + 1] : 0.f;
        v.z = (tt + 2 < T_) ? Xr[tt + 2] : 0.f;
        v.w = (tt + 3 < T_) ? Xr[tt + 3] : 0.f;
      }
      tile[cl][tq + j * 4 + 0] = v.x; tile[cl][tq + j * 4 + 1] = v.y;
      tile[cl][tq + j * 4 + 2] = v.z; tile[cl][tq + j * 4 + 3] = v.w;
    }
  }
  __syncthreads();
  {
    const int tl = tid >> 2, cq = (tid & 3) * 16;
    const int t = t0 + tl;
    if (t < T_) {
      unsigned short* dst = Xt + ((size_t)b * TP_ + t) * 256 + c0 + cq;
      s8v u0, u1;
#pragma unroll
      for (int j = 0; j < 16; ++j) {
        int c = c0 + cq + j;
        float sc = rs * g[c];
        float oc = bt[c] - mean * sc;
        unsigned short uu = f2bf(tile[cq + j][tl] * sc + oc);
        if (j < 8) u0[j] = (short)uu; else u1[j - 8] = (short)uu;
      }
      *(s8v*)dst = u0;
      *(s8v*)(dst + 8) = u1;
    }
  }
}

// ---------------- feature_r: OUTS [t][128] fp32 -> feat [128][t] fp32 ------
__global__ __launch_bounds__(256) void tfeat(const float* __restrict__ O,
                                             float* __restrict__ F) {
  const int b = blockIdx.z, c0 = blockIdx.y * 64, t0 = blockIdx.x * 64;
  __shared__ float tile[64][65];
  const int tid = threadIdx.x;
  {
    const int tr = tid >> 2, cq = (tid & 3) * 16;
    const int t = t0 + tr;
#pragma unroll
    for (int j = 0; j < 4; ++j) {
      float4 v = make_float4(0.f, 0.f, 0.f, 0.f);
      if (t < T_) v = *(const float4*)(O + ((size_t)b * TP_ + t) * 128 + c0 + cq + j * 4);
      tile[tr][cq + j * 4 + 0] = v.x; tile[tr][cq + j * 4 + 1] = v.y;
      tile[tr][cq + j * 4 + 2] = v.z; tile[tr][cq + j * 4 + 3] = v.w;
    }
  }
  __syncthreads();
  {
    const int cl = tid >> 2, tq = (tid & 3) * 16;
    float* Fr = F + ((size_t)b * 128 + c0 + cl) * T_;
#pragma unroll
    for (int j = 0; j < 4; ++j) {
      int tt = t0 + tq + j * 4;
      if (tt + 3 < T_) {
        float4 v = make_float4(tile[tq + j * 4 + 0][cl], tile[tq + j * 4 + 1][cl],
                               tile[tq + j * 4 + 2][cl], tile[tq + j * 4 + 3][cl]);
        *(float4*)(Fr + tt) = v;
      } else {
#pragma unroll
        for (int e = 0; e < 4; ++e)
          if (tt + e < T_) Fr[tt + e] = tile[tq + j * 4 + e][cl];
      }
    }
  }
}

// ---------------- clean bf16 MFMA GEMM -------------------------------------
// D[m][t] = A[m][:] . B[t][:], A [M][K] bf16, B [b][TP][K] bf16.
// Tile 64m x 128t x 64k, 4 waves (wave w owns t-cols 32w..32w+31).
// Staging: global_load_lds_dwordx4 with XOR k-slot swizzle (src and read).
// EPI 0: O0 fp32 [t][128] = v+bias, Obf bf16 shadow           (bn1)
// EPI 1: prelu -> Obf bf16 [t][512], + masked GN stats         (pw)
// EPI 2: GN2-folded: res half RMW O0 fp32 + Obf shadow; skip half RMW O1
// EPI 3: masked fp32 scatter O0[b][256][4000] = v+bias         (heads)
template <int EPI>
__global__ __launch_bounds__(256) void mm2(
    const unsigned short* __restrict__ A, const unsigned short* __restrict__ Bmat,
    int K, const float* __restrict__ bias,
    float* __restrict__ O0, float* __restrict__ O1, unsigned short* __restrict__ Obf,
    const float* __restrict__ alphaO, float* __restrict__ statsOut,
    const float* __restrict__ statsIn, float invN,
    const float* __restrict__ Uc, const float* __restrict__ Vc,
    const float* __restrict__ rb, const float* __restrict__ sb) {
  __shared__ unsigned short As[64 * 64];
  __shared__ unsigned short Bs[128 * 64];
  __shared__ float red[512];
  const int b = blockIdx.z;
  const int m0 = blockIdx.y * 64;
  const int t0 = blockIdx.x * 128;
  const int tid = threadIdx.x;
  const int lane = tid & 63;
  const int w = tid >> 6;
  const int lt = lane & 15, lg = lane >> 4;
  const unsigned short* Bb = Bmat + (size_t)b * TP_ * K;

  f32x4 acc[4][2];
#pragma unroll
  for (int i = 0; i < 4; ++i)
#pragma unroll
    for (int j = 0; j < 2; ++j) acc[i][j] = (f32x4){0.f, 0.f, 0.f, 0.f};

  // staging: chunk = 8 rows x 64k = 1KB; lane l -> row +l>>3, k-slot (l&7)^(l>>3)
  const int lr = lane >> 3;
  const int lk = ((lane & 7) ^ lr) * 8;

  for (int k0 = 0; k0 < K; k0 += 64) {
#pragma unroll
    for (int c = 0; c < 2; ++c) {
      const int ch = w * 2 + c;
      g2lds16(A + (size_t)(m0 + ch * 8 + lr) * K + (k0 + lk), &As[ch * 512]);
    }
#pragma unroll
    for (int c = 0; c < 4; ++c) {
      const int ch = w * 4 + c;
      g2lds16(Bb + (size_t)(t0 + ch * 8 + lr) * K + (k0 + lk), &Bs[ch * 512]);
    }
    __syncthreads();   // drains vmcnt before barrier (compiler-inserted)
#pragma unroll
    for (int ks = 0; ks < 2; ++ks) {
      s8v af[4], bf[2];
#pragma unroll
      for (int i = 0; i < 4; ++i) {
        const int R = i * 16 + lt;
        af[i] = *(const s8v*)&As[R * 64 + (((ks * 4 + lg) ^ (lt & 7)) * 8)];
      }
#pragma unroll
      for (int j = 0; j < 2; ++j) {
        const int R = w * 32 + j * 16 + lt;
        bf[j] = *(const s8v*)&Bs[R * 64 + (((ks * 4 + lg) ^ (lt & 7)) * 8)];
      }
#pragma unroll
      for (int i = 0; i < 4; ++i)
#pragma unroll
        for (int j = 0; j < 2; ++j)
          acc[i][j] = __builtin_amdgcn_mfma_f32_16x16x32_bf16(af[i], bf[j], acc[i][j], 0, 0, 0);
    }
    __syncthreads();
  }

  // ---- epilogues. D: row m = i*16+lg*4+r, col t = t0 + w*32 + j*16 + lt
  if constexpr (EPI == 0) {
#pragma unroll
    for (int i = 0; i < 4; ++i) {
      const int mg = m0 + i * 16 + lg * 4;
      float4 bi = *(const float4*)(bias + mg);
#pragma unroll
      for (int j = 0; j < 2; ++j) {
        const int t = t0 + w * 32 + j * 16 + lt;
        f32x4 v = acc[i][j];
        float nv[4] = {v[0] + bi.x, v[1] + bi.y, v[2] + bi.z, v[3] + bi.w};
        *(float4*)(O0 + ((size_t)b * TP_ + t) * 128 + mg) =
            make_float4(nv[0], nv[1], nv[2], nv[3]);
        u16x4 pk;
#pragma unroll
        for (int r = 0; r < 4; ++r) pk[r] = f2bf(nv[r]);
        *(u16x4*)(Obf + ((size_t)b * TP_ + t) * 128 + mg) = pk;
      }
    }
  } else if constexpr (EPI == 1) {
    const float aO = alphaO[0];
    float s1 = 0.f, s2 = 0.f;
#pragma unroll
    for (int i = 0; i < 4; ++i) {
      const int mg = m0 + i * 16 + lg * 4;
      float4 bi = *(const float4*)(bias + mg);
      float bv[4] = {bi.x, bi.y, bi.z, bi.w};
#pragma unroll
      for (int j = 0; j < 2; ++j) {
        const int t = t0 + w * 32 + j * 16 + lt;
        f32x4 v = acc[i][j];
        u16x4 pk;
#pragma unroll
        for (int r = 0; r < 4; ++r) {
          float f = v[r] + bv[r];
          f = f >= 0.f ? f : aO * f;
          pk[r] = f2bf(f);
        }
        *(u16x4*)(Obf + ((size_t)b * TP_ + t) * 512 + mg) = pk;
        if (t < T_) {
#pragma unroll
          for (int r = 0; r < 4; ++r) { float f = bf2f(pk[r]); s1 += f; s2 += f * f; }
        }
      }
    }
    red[tid] = s1; red[256 + tid] = s2;
    __syncthreads();
    for (int off = 128; off > 0; off >>= 1) {
      if (tid < off) {
        red[tid] += red[tid + off];
        red[256 + tid] += red[256 + tid + off];
      }
      __syncthreads();
    }
    if (tid == 0) {
      atomicAdd(&statsOut[b * 2 + 0], red[0]);
      atomicAdd(&statsOut[b * 2 + 1], red[256]);
    }
  } else if constexpr (EPI == 2) {
    const float mean = statsIn[b * 2] * invN;
    const float rsv = rsqrtf(statsIn[b * 2 + 1] * invN - mean * mean + 1e-8f);
#pragma unroll
    for (int i = 0; i < 4; ++i) {
      const int mgb = m0 + i * 16 + lg * 4;   // 0..255
      float cc[4];
#pragma unroll
      for (int r = 0; r < 4; ++r) {
        const int mg = mgb + r;
        cc[r] = Vc[mg] - mean * rsv * Uc[mg] +
                ((m0 < 128) ? rb[mg] : sb[mg - 128]);
      }
#pragma unroll
      for (int j = 0; j < 2; ++j) {
        const int t = t0 + w * 32 + j * 16 + lt;
        f32x4 v = acc[i][j];
        if (m0 < 128) {
          float* p = O0 + ((size_t)b * TP_ + t) * 128 + mgb;
          float4 old = *(float4*)p;
          float nv[4] = {old.x + rsv * v[0] + cc[0], old.y + rsv * v[1] + cc[1],
                         old.z + rsv * v[2] + cc[2], old.w + rsv * v[3] + cc[3]};
          *(float4*)p = make_float4(nv[0], nv[1], nv[2], nv[3]);
          u16x4 pk;
#pragma unroll
          for (int r = 0; r < 4; ++r) pk[r] = f2bf(nv[r]);
          *(u16x4*)(Obf + ((size_t)b * TP_ + t) * 128 + mgb) = pk;
        } else {
          float* p = O1 + ((size_t)b * TP_ + t) * 128 + (mgb - 128);
          float4 old = *(float4*)p;
          *(float4*)p = make_float4(old.x + rsv * v[0] + cc[0],
                                    old.y + rsv * v[1] + cc[1],
                                    old.z + rsv * v[2] + cc[2],
                                    old.w + rsv * v[3] + cc[3]);
        }
      }
    }
  } else {  // EPI 3
#pragma unroll
    for (int i = 0; i < 4; ++i) {
      const int mg = m0 + i * 16 + lg * 4;
#pragma unroll
      for (int j = 0; j < 2; ++j) {
        const int t = t0 + w * 32 + j * 16 + lt;
        if (t < T_) {
          f32x4 v = acc[i][j];
#pragma unroll
          for (int r = 0; r < 4; ++r)
            O0[((size_t)b * 256 + mg + r) * T_ + t] = v[r] + bias[mg + r];
        }
      }
    }
  }
}

// ---------------- depthwise dilated conv, [t][h] layout --------------------
__global__ __launch_bounds__(256) void dw2(
    const unsigned short* __restrict__ Y, unsigned short* __restrict__ U,
    const float* __restrict__ dww, const float* __restrict__ dwb,
    const float* __restrict__ g1, const float* __restrict__ b1,
    const float* __restrict__ p2p, const float* __restrict__ sIn, float invN,
    float* __restrict__ sOut, int dil) {
  const int b = blockIdx.y;
  const int tid = threadIdx.x;
  const int hc = (tid & 63) * 8;
  const int tbase = blockIdx.x * 16 + (tid >> 6) * 4;

  const float mean = sIn[b * 2] * invN;
  const float rs = rsqrtf(sIn[b * 2 + 1] * invN - mean * mean + 1e-8f);
  float sA[8], oA[8], w0[8], w1[8], w2[8], bb[8];
#pragma unroll
  for (int j = 0; j < 8; ++j) {
    sA[j] = rs * g1[hc + j];
    oA[j] = b1[hc + j] - mean * sA[j];
    w0[j] = dww[(hc + j) * 3 + 0];
    w1[j] = dww[(hc + j) * 3 + 1];
    w2[j] = dww[(hc + j) * 3 + 2];
    bb[j] = dwb[hc + j];
  }
  const float alpha = p2p[0];
  const unsigned short* Yb = Y + (size_t)b * TP_ * 512;
  unsigned short* Ub = U + (size_t)b * TP_ * 512;
  float s1 = 0.f, s2 = 0.f;
#pragma unroll
  for (int i = 0; i < 4; ++i) {
    const int t = tbase + i;
    const int tm = t - dil, tp = t + dil;
    const bool vm = (tm >= 0), vp = (tp < T_);
    s8v xm = {0, 0, 0, 0, 0, 0, 0, 0};
    s8v xp = {0, 0, 0, 0, 0, 0, 0, 0};
    s8v x0 = *(const s8v*)(Yb + (size_t)t * 512 + hc);
    if (vm) xm = *(const s8v*)(Yb + (size_t)tm * 512 + hc);
    if (vp) xp = *(const s8v*)(Yb + (size_t)tp * 512 + hc);
    s8v out;
#pragma unroll
    for (int j = 0; j < 8; ++j) {
      float fm = vm ? (bf2f((unsigned short)xm[j]) * sA[j] + oA[j]) : 0.f;
      float f0 = bf2f((unsigned short)x0[j]) * sA[j] + oA[j];
      float fp = vp ? (bf2f((unsigned short)xp[j]) * sA[j] + oA[j]) : 0.f;
      float v = fmaf(w0[j], fm, fmaf(w1[j], f0, fmaf(w2[j], fp, bb[j])));
      v = v >= 0.f ? v : alpha * v;
      unsigned short u = f2bf(v);
      out[j] = (short)u;
      float f = bf2f(u);
      s1 += f; s2 += f * f;
    }
    *(s8v*)(Ub + (size_t)t * 512 + hc) = out;
  }
  __shared__ float red[512];
  red[tid] = s1; red[256 + tid] = s2;
  __syncthreads();
  for (int off = 128; off > 0; off >>= 1) {
    if (tid < off) {
      red[tid] += red[tid + off];
      red[256 + tid] += red[256 + tid + off];
    }
    __syncthreads();
  }
  if (tid == 0) {
    atomicAdd(&sOut[b * 2 + 0], red[0]);
    atomicAdd(&sOut[b * 2 + 1], red[256]);
  }
}

// ---------------------------------------------------------------------------
extern "C" void kernel_launch(void* const* d_in, const int* in_sizes, int n_in,
                              void* d_out, int out_size, void* d_ws, size_t ws_size,
                              hipStream_t stream) {
  (void)in_sizes; (void)n_in; (void)out_size; (void)ws_size;
  const float* input = (const float*)d_in[0];
  const float* ln1_g = (const float*)d_in[1];
  const float* ln1_b = (const float*)d_in[2];
  const float* bn1_w = (const float*)d_in[3];
  const float* bn1_b = (const float*)d_in[4];
  const float* pw_w  = (const float*)d_in[5];
  const float* pw_b  = (const float*)d_in[6];
  const float* dw_w  = (const float*)d_in[7];
  const float* dw_b  = (const float*)d_in[8];
  const float* res_w = (const float*)d_in[9];
  const float* res_b = (const float*)d_in[10];
  const float* sk_w  = (const float*)d_in[11];
  const float* sk_b  = (const float*)d_in[12];
  const float* p1    = (const float*)d_in[13];
  const float* p2    = (const float*)d_in[14];
  const float* n1g   = (const float*)d_in[15];
  const float* n1b   = (const float*)d_in[16];
  const float* n2g   = (const float*)d_in[17];
  const float* n2b   = (const float*)d_in[18];
  const float* h1_p  = (const float*)d_in[19];
  const float* h1_w  = (const float*)d_in[20];
  const float* h1_b  = (const float*)d_in[21];
  const float* h2_p  = (const float*)d_in[22];
  const float* h2_w  = (const float*)d_in[23];
  const float* h2_b  = (const float*)d_in[24];

  float* out1 = (float*)d_out;
  float* out2 = out1 + 4096000;   // [4,256,4000]
  float* feat = out1 + 8192000;   // [4,128,4000]

  char* base = (char*)d_ws;
  float* OUTS  = (float*)base;                  base += (size_t)B_ * TP_ * 128 * 4;
  float* SKIP  = (float*)base;                  base += (size_t)B_ * TP_ * 128 * 4;
  float* OUT2  = (float*)base;                  base += (size_t)B_ * TP_ * 128 * 4;
  float* SKIP2 = (float*)base;                  base += (size_t)B_ * TP_ * 128 * 4;
  unsigned short* OUTbf  = (unsigned short*)base; base += (size_t)B_ * TP_ * 128 * 2;
  unsigned short* OUT2bf = (unsigned short*)base; base += (size_t)B_ * TP_ * 128 * 2;
  unsigned short* Ybuf = (unsigned short*)base; base += (size_t)B_ * TP_ * 512 * 2;
  unsigned short* Ubuf = (unsigned short*)base; base += (size_t)B_ * TP_ * 512 * 2;
  unsigned short* Xt   = (unsigned short*)base; base += (size_t)B_ * TP_ * 256 * 2;
  unsigned short* SKbf = (unsigned short*)base; base += (size_t)B_ * TP_ * 128 * 2;
  unsigned short* Wpw  = (unsigned short*)base; base += (size_t)32 * 512 * 128 * 2;
  unsigned short* Wg   = (unsigned short*)base; base += (size_t)32 * 256 * 512 * 2;
  unsigned short* Wbn  = (unsigned short*)base; base += (size_t)128 * 256 * 2;
  unsigned short* Wh1  = (unsigned short*)base; base += (size_t)256 * 128 * 2;
  unsigned short* Wh2  = (unsigned short*)base; base += (size_t)256 * 128 * 2;
  float* UVu   = (float*)base;                  base += (size_t)32 * 256 * 4;
  float* UVv   = (float*)base;                  base += (size_t)32 * 256 * 4;
  float* STATS = (float*)base;

  hipMemsetAsync(STATS, 0, 65 * 8 * sizeof(float), stream);
  hipMemsetAsync(SKIP, 0, (size_t)B_ * TP_ * 128 * sizeof(float), stream);

  const float invN_in = 1.0f / (256.0f * 4000.0f);
  const float invN_h  = 1.0f / (512.0f * 4000.0f);

  // weight prep
  cvt_bf<<<2048, 256, 0, stream>>>(pw_w, Wpw, 32 * 512 * 128);
  cvt_bf<<<128, 256, 0, stream>>>(bn1_w, Wbn, 128 * 256);
  cvt_bf<<<128, 256, 0, stream>>>(h1_w, Wh1, 256 * 128);
  cvt_bf<<<128, 256, 0, stream>>>(h2_w, Wh2, 256 * 128);
  fold_rs<<<32 * 256, 256, 0, stream>>>(res_w, sk_w, n2g, n2b, Wg, UVu, UVv);

  // input GN -> bf16 [t][256] -> bottleneck GEMM
  gn_stats<<<dim3(64, B_), 256, 0, stream>>>(input, STATS, 256 * T_);
  tin<<<dim3(63, 4, B_), 256, 0, stream>>>(input, Xt, ln1_g, ln1_b, STATS, invN_in);
  mm2<0><<<dim3(32, 2, B_), 256, 0, stream>>>(
      Wbn, Xt, 256, bn1_b, OUTS, nullptr, OUTbf, nullptr, nullptr,
      nullptr, 0.f, nullptr, nullptr, nullptr, nullptr);

  auto run_block = [&](int i, float* OS, float* SK, unsigned short* OSbf) {
    float* sA = STATS + (size_t)(1 + 2 * i) * 8;
    float* sB = STATS + (size_t)(2 + 2 * i) * 8;
    mm2<1><<<dim3(32, 8, B_), 256, 0, stream>>>(
        Wpw + (size_t)i * 512 * 128, OSbf, 128, pw_b + (size_t)i * 512,
        nullptr, nullptr, Ybuf, p1 + i, sA, nullptr, 0.f,
        nullptr, nullptr, nullptr, nullptr);
    dw2<<<dim3(250, B_), 256, 0, stream>>>(
        Ybuf, Ubuf, dw_w + (size_t)i * 512 * 3, dw_b + (size_t)i * 512,
        n1g + (size_t)i * 512, n1b + (size_t)i * 512, p2 + i, sA, invN_h, sB,
        1 << (i & 7));
    mm2<2><<<dim3(32, 4, B_), 256, 0, stream>>>(
        Wg + (size_t)i * 256 * 512, Ubuf, 512, nullptr, OS, SK, OSbf,
        nullptr, nullptr, sB, invN_h, UVu + (size_t)i * 256, UVv + (size_t)i * 256,
        res_b + (size_t)i * 128, sk_b + (size_t)i * 128);
  };

  for (int i = 0; i < 8; ++i) {
    run_block(i, OUTS, SKIP, OUTbf);
    if (i == 7) tfeat<<<dim3(63, 2, B_), 256, 0, stream>>>(OUTS, feat);
  }
  for (int i = 8; i < 16; ++i) run_block(i, OUTS, SKIP, OUTbf);

  hipMemcpyAsync(OUT2, OUTS, (size_t)B_ * TP_ * 128 * 4, hipMemcpyDeviceToDevice, stream);
  hipMemcpyAsync(OUT2bf, OUTbf, (size_t)B_ * TP_ * 128 * 2, hipMemcpyDeviceToDevice, stream);
  hipMemcpyAsync(SKIP2, SKIP, (size_t)B_ * TP_ * 128 * 4, hipMemcpyDeviceToDevice, stream);

  for (int i = 16; i < 24; ++i) run_block(i, OUTS, SKIP, OUTbf);
  for (int i = 24; i < 32; ++i) run_block(i, OUT2, SKIP2, OUT2bf);

  // heads: out = h_w @ prelu(skip) + h_b
  prelu_cvt<<<2048, 256, 0, stream>>>(SKIP, SKbf, h1_p, B_ * TP_ * 128);
  mm2<3><<<dim3(32, 4, B_), 256, 0, stream>>>(
      Wh1, SKbf, 128, h1_b, out1, nullptr, nullptr, nullptr, nullptr,
      nullptr, 0.f, nullptr, nullptr, nullptr, nullptr);
  prelu_cvt<<<2048, 256, 0, stream>>>(SKIP2, SKbf, h2_p, B_ * TP_ * 128);
  mm2<3><<<dim3(32, 4, B_), 256, 0, stream>>>(
      Wh2, SKbf, 128, h2_b, out2, nullptr, nullptr, nullptr, nullptr,
      nullptr, 0.f, nullptr, nullptr, nullptr, nullptr);
}